// Round 1
// baseline (5657.507 us; speedup 1.0000x reference)
//
#include <hip/hip_runtime.h>
#include <math.h>

#define SLOPE 0.2f

static __device__ __forceinline__ float leaky(float x) {
  return x > 0.f ? x : SLOPE * x;
}

// ---------------- GEMM1: C[M,256] = A[M,K] @ B[K,256], K=1433 ----------------
// 64 rows x 256 cols per block, BK=16, fp32, LDS staged (A transposed).
__global__ __launch_bounds__(256) void gemm1_kernel(
    const float* __restrict__ A, const float* __restrict__ B,
    float* __restrict__ C, int M, int K) {
  __shared__ float As[16][68];    // [k][m], padded
  __shared__ float Bs[16][260];   // [k][n], padded
  const int t = threadIdx.x;
  const int tx = t & 15, ty = t >> 4;
  const int row0 = blockIdx.x * 64;

  float acc[4][4][4];  // [row i][col group u][col j]
#pragma unroll
  for (int i = 0; i < 4; ++i)
#pragma unroll
    for (int u = 0; u < 4; ++u)
#pragma unroll
      for (int j = 0; j < 4; ++j) acc[i][u][j] = 0.f;

  const int ar = t >> 2, aks = (t & 3) * 4;
  const int bkr = t >> 4, btx = t & 15;

  for (int k0 = 0; k0 < K; k0 += 16) {
    // A tile -> As transposed
    {
      int grow = row0 + ar;
#pragma unroll
      for (int j = 0; j < 4; ++j) {
        int gk = k0 + aks + j;
        float v = 0.f;
        if (grow < M && gk < K) v = A[(long)grow * K + gk];
        As[aks + j][ar] = v;
      }
    }
    // B tile
    {
      int gk = k0 + bkr;
#pragma unroll
      for (int u = 0; u < 4; ++u) {
        float4 v = make_float4(0.f, 0.f, 0.f, 0.f);
        int col = u * 64 + btx * 4;
        if (gk < K) v = *(const float4*)(B + (long)gk * 256 + col);
        *(float4*)&Bs[bkr][col] = v;
      }
    }
    __syncthreads();
#pragma unroll
    for (int kk = 0; kk < 16; ++kk) {
      float4 a = *(const float4*)&As[kk][ty * 4];
      float av[4] = {a.x, a.y, a.z, a.w};
#pragma unroll
      for (int u = 0; u < 4; ++u) {
        float4 b = *(const float4*)&Bs[kk][u * 64 + tx * 4];
        float bv[4] = {b.x, b.y, b.z, b.w};
#pragma unroll
        for (int i = 0; i < 4; ++i)
#pragma unroll
          for (int j = 0; j < 4; ++j) acc[i][u][j] += av[i] * bv[j];
      }
    }
    __syncthreads();
  }
#pragma unroll
  for (int i = 0; i < 4; ++i) {
    int row = row0 + ty * 4 + i;
    if (row < M) {
#pragma unroll
      for (int u = 0; u < 4; ++u) {
        float4 v = make_float4(acc[i][u][0], acc[i][u][1], acc[i][u][2], acc[i][u][3]);
        *(float4*)(C + (long)row * 256 + u * 64 + tx * 4) = v;
      }
    }
  }
}

// ---------------- per-node attention logits, layer 1 ----------------
__global__ void alpha1_kernel(const float* __restrict__ h1,
    const float* __restrict__ a_src, const float* __restrict__ a_dst,
    float* __restrict__ as_o, float* __restrict__ ad_o, int N) {
  int i = blockIdx.x * blockDim.x + threadIdx.x;  // i = n*8+h
  if (i >= N * 8) return;
  int h = i & 7;
  const float* hp = h1 + (long)(i >> 3) * 256 + h * 32;
  const float* sp = a_src + h * 32;
  const float* dp = a_dst + h * 32;
  float s1 = 0.f, s2 = 0.f;
#pragma unroll
  for (int c = 0; c < 32; c += 4) {
    float4 v = *(const float4*)(hp + c);
    float4 ws = *(const float4*)(sp + c);
    float4 wd = *(const float4*)(dp + c);
    s1 += v.x * ws.x + v.y * ws.y + v.z * ws.z + v.w * ws.w;
    s2 += v.x * wd.x + v.y * wd.y + v.z * wd.z + v.w * wd.w;
  }
  as_o[i] = s1;
  ad_o[i] = s2;
}

// ---------------- softmax denominator (no max-subtract: logits are tiny) ----
__global__ void denom_kernel(const int* __restrict__ src, const int* __restrict__ dst,
    const float* __restrict__ as_, const float* __restrict__ ad_,
    float* __restrict__ denom, int E, int N) {
  int e = blockIdx.x * blockDim.x + threadIdx.x;
  if (e >= E + N) return;
  int s, d;
  if (e < E) { s = src[e]; d = dst[e]; } else { s = e - E; d = s; }
#pragma unroll
  for (int h = 0; h < 8; ++h) {
    float lg = leaky(as_[s * 8 + h] + ad_[d * 8 + h]);
    atomicAdd(&denom[d * 8 + h], __expf(lg));
  }
}

// ---------------- layer-1 aggregation: 64 threads/edge, f32 atomics ---------
__global__ __launch_bounds__(256) void agg1_kernel(const int* __restrict__ src,
    const int* __restrict__ dst, const float* __restrict__ as_,
    const float* __restrict__ ad_, const float* __restrict__ denom,
    const float* __restrict__ h1, float* __restrict__ agg, int E, int N) {
  long gid = (long)blockIdx.x * 256 + threadIdx.x;
  int e = (int)(gid >> 6);
  if (e >= E + N) return;
  int l = (int)gid & 63;
  int s, d;
  if (e < E) { s = src[e]; d = dst[e]; } else { s = e - E; d = s; }
  int h = l >> 3;
  float lg = leaky(as_[s * 8 + h] + ad_[d * 8 + h]);
  float alpha = __expf(lg) / denom[d * 8 + h];
  float4 v = *(const float4*)(h1 + (long)s * 256 + l * 4);
  float* op = agg + (long)d * 256 + l * 4;
  atomicAdd(op + 0, v.x * alpha);
  atomicAdd(op + 1, v.y * alpha);
  atomicAdd(op + 2, v.z * alpha);
  atomicAdd(op + 3, v.w * alpha);
}

// ---------------- bias + ELU (in place) ----------------
__global__ void bias_elu_kernel(float* __restrict__ buf,
    const float* __restrict__ bias, int total4) {
  int i = blockIdx.x * blockDim.x + threadIdx.x;
  if (i >= total4) return;
  float4 v = *(float4*)(buf + (long)i * 4);
  int c = (i & 63) * 4;
  float4 b = *(const float4*)(bias + c);
  v.x += b.x; v.y += b.y; v.z += b.z; v.w += b.w;
  v.x = v.x > 0.f ? v.x : expm1f(v.x);
  v.y = v.y > 0.f ? v.y : expm1f(v.y);
  v.z = v.z > 0.f ? v.z : expm1f(v.z);
  v.w = v.w > 0.f ? v.w : expm1f(v.w);
  *(float4*)(buf + (long)i * 4) = v;
}

// ---------------- GEMM2 (K=256, N=56) + fused alpha2 ----------------
// block = 256 threads = 32 rows x 8 heads; W2 staged whole in LDS (57344 B)
__global__ __launch_bounds__(256) void gemm2_kernel(const float* __restrict__ act,
    const float* __restrict__ W2, const float* __restrict__ a_src2,
    const float* __restrict__ a_dst2, float* __restrict__ h2,
    float* __restrict__ as_o, float* __restrict__ ad_o, int N) {
  __shared__ float Ws[256 * 56];
  for (int i = threadIdx.x; i < 256 * 56; i += 256) Ws[i] = W2[i];
  __syncthreads();
  int n = blockIdx.x * 32 + (threadIdx.x >> 3);
  int h = threadIdx.x & 7;
  if (n >= N) return;
  const float* ap = act + (long)n * 256;
  float acc[7] = {0.f, 0.f, 0.f, 0.f, 0.f, 0.f, 0.f};
  for (int k0 = 0; k0 < 256; k0 += 4) {
    float4 a = *(const float4*)(ap + k0);
    float av[4] = {a.x, a.y, a.z, a.w};
#pragma unroll
    for (int kk = 0; kk < 4; ++kk) {
      const float* wp = &Ws[(k0 + kk) * 56 + h * 7];
#pragma unroll
      for (int j = 0; j < 7; ++j) acc[j] += av[kk] * wp[j];
    }
  }
  float* hp = h2 + (long)n * 56 + h * 7;
  float s1 = 0.f, s2 = 0.f;
#pragma unroll
  for (int j = 0; j < 7; ++j) {
    hp[j] = acc[j];
    s1 += acc[j] * a_src2[h * 7 + j];
    s2 += acc[j] * a_dst2[h * 7 + j];
  }
  as_o[n * 8 + h] = s1;
  ad_o[n * 8 + h] = s2;
}

// ---------------- init output with bias2 ----------------
__global__ void out_init_kernel(float* __restrict__ out,
    const float* __restrict__ bias, int N) {
  int i = blockIdx.x * blockDim.x + threadIdx.x;
  if (i >= N * 56) return;
  out[i] = bias[i % 56];
}

// ---------------- layer-2 aggregation: thread per (edge, head) --------------
__global__ void agg2_kernel(const int* __restrict__ src, const int* __restrict__ dst,
    const float* __restrict__ as_, const float* __restrict__ ad_,
    const float* __restrict__ denom, const float* __restrict__ h2,
    float* __restrict__ out, int E, int N) {
  long gid = (long)blockIdx.x * 256 + threadIdx.x;
  int e = (int)(gid >> 3);
  if (e >= E + N) return;
  int h = (int)gid & 7;
  int s, d;
  if (e < E) { s = src[e]; d = dst[e]; } else { s = e - E; d = s; }
  float lg = leaky(as_[s * 8 + h] + ad_[d * 8 + h]);
  float alpha = __expf(lg) / denom[d * 8 + h];
  const float* hp = h2 + (long)s * 56 + h * 7;
  float* op = out + (long)d * 56 + h * 7;
#pragma unroll
  for (int j = 0; j < 7; ++j) atomicAdd(op + j, hp[j] * alpha);
}

extern "C" void kernel_launch(void* const* d_in, const int* in_sizes, int n_in,
                              void* d_out, int out_size, void* d_ws, size_t ws_size,
                              hipStream_t stream) {
  const float* x    = (const float*)d_in[0];
  const int*   ei   = (const int*)d_in[1];
  const float* W1   = (const float*)d_in[2];
  const float* asr1 = (const float*)d_in[3];
  const float* adt1 = (const float*)d_in[4];
  const float* b1   = (const float*)d_in[5];
  const float* W2   = (const float*)d_in[6];
  const float* asr2 = (const float*)d_in[7];
  const float* adt2 = (const float*)d_in[8];
  const float* b2   = (const float*)d_in[9];
  float* out = (float*)d_out;

  const int N = in_sizes[0] / 1433;
  const int E = in_sizes[1] / 2;
  const int* src = ei;
  const int* dst = ei + E;

  float* ws = (float*)d_ws;
  float* h1  = ws; ws += (long)N * 256;
  float* act = ws; ws += (long)N * 256;   // agg target, ELU'd in place
  float* h2  = ws; ws += (long)N * 56;
  float* as1 = ws; ws += N * 8;
  float* ad1 = ws; ws += N * 8;
  float* dn1 = ws; ws += N * 8;
  float* as2 = ws; ws += N * 8;
  float* ad2 = ws; ws += N * 8;
  float* dn2 = ws; ws += N * 8;

  hipMemsetAsync(dn1, 0, (size_t)N * 8 * sizeof(float), stream);
  hipMemsetAsync(dn2, 0, (size_t)N * 8 * sizeof(float), stream);
  hipMemsetAsync(act, 0, (size_t)N * 256 * sizeof(float), stream);

  dim3 blk(256);

  gemm1_kernel<<<dim3((N + 63) / 64), blk, 0, stream>>>(x, W1, h1, N, 1433);
  alpha1_kernel<<<dim3((N * 8 + 255) / 256), blk, 0, stream>>>(h1, asr1, adt1, as1, ad1, N);
  denom_kernel<<<dim3((E + N + 255) / 256), blk, 0, stream>>>(src, dst, as1, ad1, dn1, E, N);
  {
    long tot = (long)(E + N) * 64;
    agg1_kernel<<<dim3((unsigned)((tot + 255) / 256)), blk, 0, stream>>>(
        src, dst, as1, ad1, dn1, h1, act, E, N);
  }
  bias_elu_kernel<<<dim3((N * 64 + 255) / 256), blk, 0, stream>>>(act, b1, N * 64);
  gemm2_kernel<<<dim3((N + 31) / 32), blk, 0, stream>>>(act, W2, asr2, adt2, h2, as2, ad2, N);
  denom_kernel<<<dim3((E + N + 255) / 256), blk, 0, stream>>>(src, dst, as2, ad2, dn2, E, N);
  out_init_kernel<<<dim3((N * 56 + 255) / 256), blk, 0, stream>>>(out, b2, N);
  {
    long tot = (long)(E + N) * 8;
    agg2_kernel<<<dim3((unsigned)((tot + 255) / 256)), blk, 0, stream>>>(
        src, dst, as2, ad2, dn2, h2, out, E, N);
  }
}

// Round 2
// 1312.237 us; speedup vs baseline: 4.3113x; 4.3113x over previous
//
#include <hip/hip_runtime.h>
#include <math.h>

#define SLOPE 0.2f

static __device__ __forceinline__ float leaky(float x) {
  return x > 0.f ? x : SLOPE * x;
}

// ---------------- GEMM1: C[M,256] = A[M,K] @ B[K,256], K=1433 ----------------
__global__ __launch_bounds__(256) void gemm1_kernel(
    const float* __restrict__ A, const float* __restrict__ B,
    float* __restrict__ C, int M, int K) {
  __shared__ float As[16][68];    // [k][m], padded
  __shared__ float Bs[16][260];   // [k][n], padded
  const int t = threadIdx.x;
  const int tx = t & 15, ty = t >> 4;
  const int row0 = blockIdx.x * 64;

  float acc[4][4][4];
#pragma unroll
  for (int i = 0; i < 4; ++i)
#pragma unroll
    for (int u = 0; u < 4; ++u)
#pragma unroll
      for (int j = 0; j < 4; ++j) acc[i][u][j] = 0.f;

  const int ar = t >> 2, aks = (t & 3) * 4;
  const int bkr = t >> 4, btx = t & 15;

  for (int k0 = 0; k0 < K; k0 += 16) {
    {
      int grow = row0 + ar;
#pragma unroll
      for (int j = 0; j < 4; ++j) {
        int gk = k0 + aks + j;
        float v = 0.f;
        if (grow < M && gk < K) v = A[(long)grow * K + gk];
        As[aks + j][ar] = v;
      }
    }
    {
      int gk = k0 + bkr;
#pragma unroll
      for (int u = 0; u < 4; ++u) {
        float4 v = make_float4(0.f, 0.f, 0.f, 0.f);
        int col = u * 64 + btx * 4;
        if (gk < K) v = *(const float4*)(B + (long)gk * 256 + col);
        *(float4*)&Bs[bkr][col] = v;
      }
    }
    __syncthreads();
#pragma unroll
    for (int kk = 0; kk < 16; ++kk) {
      float4 a = *(const float4*)&As[kk][ty * 4];
      float av[4] = {a.x, a.y, a.z, a.w};
#pragma unroll
      for (int u = 0; u < 4; ++u) {
        float4 b = *(const float4*)&Bs[kk][u * 64 + tx * 4];
        float bv[4] = {b.x, b.y, b.z, b.w};
#pragma unroll
        for (int i = 0; i < 4; ++i)
#pragma unroll
          for (int j = 0; j < 4; ++j) acc[i][u][j] += av[i] * bv[j];
      }
    }
    __syncthreads();
  }
#pragma unroll
  for (int i = 0; i < 4; ++i) {
    int row = row0 + ty * 4 + i;
    if (row < M) {
#pragma unroll
      for (int u = 0; u < 4; ++u) {
        float4 v = make_float4(acc[i][u][0], acc[i][u][1], acc[i][u][2], acc[i][u][3]);
        *(float4*)(C + (long)row * 256 + u * 64 + tx * 4) = v;
      }
    }
  }
}

// ---------------- per-node attention logits, layer 1 ----------------
__global__ void alpha1_kernel(const float* __restrict__ h1,
    const float* __restrict__ a_src, const float* __restrict__ a_dst,
    float* __restrict__ as_o, float* __restrict__ ad_o, int N) {
  int i = blockIdx.x * blockDim.x + threadIdx.x;  // i = n*8+h
  if (i >= N * 8) return;
  int h = i & 7;
  const float* hp = h1 + (long)(i >> 3) * 256 + h * 32;
  const float* sp = a_src + h * 32;
  const float* dp = a_dst + h * 32;
  float s1 = 0.f, s2 = 0.f;
#pragma unroll
  for (int c = 0; c < 32; c += 4) {
    float4 v = *(const float4*)(hp + c);
    float4 ws = *(const float4*)(sp + c);
    float4 wd = *(const float4*)(dp + c);
    s1 += v.x * ws.x + v.y * ws.y + v.z * ws.z + v.w * ws.w;
    s2 += v.x * wd.x + v.y * wd.y + v.z * wd.z + v.w * wd.w;
  }
  as_o[i] = s1;
  ad_o[i] = s2;
}

// ================= CSR construction =================
// counts over E real edges + N self-loops
__global__ void hist_kernel(const int* __restrict__ dst, int* __restrict__ cnt,
                            int E, int N) {
  int e = blockIdx.x * blockDim.x + threadIdx.x;
  if (e >= E + N) return;
  int d = (e < E) ? dst[e] : (e - E);
  atomicAdd(&cnt[d], 1);
}

// single-block exclusive scan of cnt[0..N) -> rowptr[0..N], cursor copy
__global__ __launch_bounds__(1024) void scan_kernel(
    const int* __restrict__ cnt, int* __restrict__ rowptr,
    int* __restrict__ cursor, int N) {
  __shared__ int part[1024];
  const int tid = threadIdx.x;
  const int chunk = (N + 1023) / 1024;
  const int base = tid * chunk;
  const int lim = min(base + chunk, N);
  int sum = 0;
  for (int i = base; i < lim; ++i) sum += cnt[i];
  part[tid] = sum;
  __syncthreads();
  for (int off = 1; off < 1024; off <<= 1) {
    int v = (tid >= off) ? part[tid - off] : 0;
    __syncthreads();
    part[tid] += v;
    __syncthreads();
  }
  int run = (tid == 0) ? 0 : part[tid - 1];
  for (int i = base; i < lim; ++i) {
    rowptr[i] = run;
    cursor[i] = run;
    run += cnt[i];
  }
  if (tid == 1023) rowptr[N] = part[1023];
}

// scatter src ids into dst-ordered CSR
__global__ void scatter_kernel(const int* __restrict__ src,
    const int* __restrict__ dst, int* __restrict__ cursor,
    int* __restrict__ csr_src, int E, int N) {
  int e = blockIdx.x * blockDim.x + threadIdx.x;
  if (e >= E + N) return;
  int s, d;
  if (e < E) { s = src[e]; d = dst[e]; } else { s = e - E; d = s; }
  int pos = atomicAdd(&cursor[d], 1);
  csr_src[pos] = s;
}

// ======== layer-1 fused aggregation: wave per dst, no atomics ========
// lane l: head h = l>>3, channels [l*4, l*4+4). Fuses softmax denom,
// normalization, bias1 add, ELU.
__global__ __launch_bounds__(256) void agg1_fused_kernel(
    const int* __restrict__ rowptr, const int* __restrict__ csr_src,
    const float* __restrict__ as_, const float* __restrict__ ad_,
    const float* __restrict__ h1, const float* __restrict__ bias,
    float* __restrict__ act, int N) {
  int d = blockIdx.x * 4 + (threadIdx.x >> 6);
  if (d >= N) return;
  int l = threadIdx.x & 63;
  int h = l >> 3;
  int rs = rowptr[d], re = rowptr[d + 1];
  float adv = ad_[d * 8 + h];
  float4 acc = make_float4(0.f, 0.f, 0.f, 0.f);
  float den = 0.f;
  for (int i = rs; i < re; ++i) {
    int s = csr_src[i];
    float a = __expf(leaky(as_[s * 8 + h] + adv));
    den += a;
    float4 v = *(const float4*)(h1 + (long)s * 256 + l * 4);
    acc.x += a * v.x; acc.y += a * v.y; acc.z += a * v.z; acc.w += a * v.w;
  }
  float inv = 1.f / den;
  float4 b = *(const float4*)(bias + l * 4);
  float4 o;
  o.x = acc.x * inv + b.x; o.y = acc.y * inv + b.y;
  o.z = acc.z * inv + b.z; o.w = acc.w * inv + b.w;
  o.x = o.x > 0.f ? o.x : expm1f(o.x);
  o.y = o.y > 0.f ? o.y : expm1f(o.y);
  o.z = o.z > 0.f ? o.z : expm1f(o.z);
  o.w = o.w > 0.f ? o.w : expm1f(o.w);
  *(float4*)(act + (long)d * 256 + l * 4) = o;
}

// ---------------- GEMM2 (K=256, N=56) + fused alpha2 ----------------
__global__ __launch_bounds__(256) void gemm2_kernel(const float* __restrict__ act,
    const float* __restrict__ W2, const float* __restrict__ a_src2,
    const float* __restrict__ a_dst2, float* __restrict__ h2,
    float* __restrict__ as_o, float* __restrict__ ad_o, int N) {
  __shared__ float Ws[256 * 56];
  for (int i = threadIdx.x; i < 256 * 56; i += 256) Ws[i] = W2[i];
  __syncthreads();
  int n = blockIdx.x * 32 + (threadIdx.x >> 3);
  int h = threadIdx.x & 7;
  if (n >= N) return;
  const float* ap = act + (long)n * 256;
  float acc[7] = {0.f, 0.f, 0.f, 0.f, 0.f, 0.f, 0.f};
  for (int k0 = 0; k0 < 256; k0 += 4) {
    float4 a = *(const float4*)(ap + k0);
    float av[4] = {a.x, a.y, a.z, a.w};
#pragma unroll
    for (int kk = 0; kk < 4; ++kk) {
      const float* wp = &Ws[(k0 + kk) * 56 + h * 7];
#pragma unroll
      for (int j = 0; j < 7; ++j) acc[j] += av[kk] * wp[j];
    }
  }
  float* hp = h2 + (long)n * 56 + h * 7;
  float s1 = 0.f, s2 = 0.f;
#pragma unroll
  for (int j = 0; j < 7; ++j) {
    hp[j] = acc[j];
    s1 += acc[j] * a_src2[h * 7 + j];
    s2 += acc[j] * a_dst2[h * 7 + j];
  }
  as_o[n * 8 + h] = s1;
  ad_o[n * 8 + h] = s2;
}

// ======== layer-2 fused aggregation: wave per dst ========
// lane l: head h = l>>3, j = l&7 (active j<7). Fuses denom + bias2.
__global__ __launch_bounds__(256) void agg2_fused_kernel(
    const int* __restrict__ rowptr, const int* __restrict__ csr_src,
    const float* __restrict__ as_, const float* __restrict__ ad_,
    const float* __restrict__ h2, const float* __restrict__ bias,
    float* __restrict__ out, int N) {
  int d = blockIdx.x * 4 + (threadIdx.x >> 6);
  if (d >= N) return;
  int l = threadIdx.x & 63;
  int h = l >> 3, j = l & 7;
  int rs = rowptr[d], re = rowptr[d + 1];
  float adv = ad_[d * 8 + h];
  float acc = 0.f, den = 0.f;
  for (int i = rs; i < re; ++i) {
    int s = csr_src[i];
    float a = __expf(leaky(as_[s * 8 + h] + adv));
    den += a;
    if (j < 7) acc += a * h2[(long)s * 56 + h * 7 + j];
  }
  if (j < 7) out[(long)d * 56 + h * 7 + j] = acc / den + bias[h * 7 + j];
}

extern "C" void kernel_launch(void* const* d_in, const int* in_sizes, int n_in,
                              void* d_out, int out_size, void* d_ws, size_t ws_size,
                              hipStream_t stream) {
  const float* x    = (const float*)d_in[0];
  const int*   ei   = (const int*)d_in[1];
  const float* W1   = (const float*)d_in[2];
  const float* asr1 = (const float*)d_in[3];
  const float* adt1 = (const float*)d_in[4];
  const float* b1   = (const float*)d_in[5];
  const float* W2   = (const float*)d_in[6];
  const float* asr2 = (const float*)d_in[7];
  const float* adt2 = (const float*)d_in[8];
  const float* b2   = (const float*)d_in[9];
  float* out = (float*)d_out;

  const int N = in_sizes[0] / 1433;
  const int E = in_sizes[1] / 2;
  const int* src = ei;
  const int* dst = ei + E;

  float* ws = (float*)d_ws;
  float* h1  = ws; ws += (long)N * 256;
  float* act = ws; ws += (long)N * 256;
  float* h2  = ws; ws += (long)N * 56;
  float* as1 = ws; ws += N * 8;
  float* ad1 = ws; ws += N * 8;
  float* as2 = ws; ws += N * 8;
  float* ad2 = ws; ws += N * 8;
  int* cnt     = (int*)ws; ws += N;
  int* rowptr  = (int*)ws; ws += N + 1;
  int* cursor  = (int*)ws; ws += N;
  int* csr_src = (int*)ws; ws += E + N;

  hipMemsetAsync(cnt, 0, (size_t)N * sizeof(int), stream);

  dim3 blk(256);

  // CSR build (overlappable with gemm1 in-stream order; cheap)
  hist_kernel<<<dim3((E + N + 255) / 256), blk, 0, stream>>>(dst, cnt, E, N);
  scan_kernel<<<dim3(1), dim3(1024), 0, stream>>>(cnt, rowptr, cursor, N);
  scatter_kernel<<<dim3((E + N + 255) / 256), blk, 0, stream>>>(
      src, dst, cursor, csr_src, E, N);

  gemm1_kernel<<<dim3((N + 63) / 64), blk, 0, stream>>>(x, W1, h1, N, 1433);
  alpha1_kernel<<<dim3((N * 8 + 255) / 256), blk, 0, stream>>>(h1, asr1, adt1, as1, ad1, N);
  agg1_fused_kernel<<<dim3((N + 3) / 4), blk, 0, stream>>>(
      rowptr, csr_src, as1, ad1, h1, b1, act, N);
  gemm2_kernel<<<dim3((N + 31) / 32), blk, 0, stream>>>(act, W2, asr2, adt2, h2, as2, ad2, N);
  agg2_fused_kernel<<<dim3((N + 3) / 4), blk, 0, stream>>>(
      rowptr, csr_src, as2, ad2, h2, b2, out, N);
}

// Round 3
// 821.781 us; speedup vs baseline: 6.8844x; 1.5968x over previous
//
#include <hip/hip_runtime.h>
#include <math.h>

typedef short s16x8 __attribute__((ext_vector_type(8)));
typedef float f32x4 __attribute__((ext_vector_type(4)));

#define SLOPE 0.2f
#define K1 1433
#define KP 1440   // K padded to multiple of 32

static __device__ __forceinline__ float leaky(float x) {
  return x > 0.f ? x : SLOPE * x;
}

static __device__ __forceinline__ unsigned short f2bf(float f) {
  unsigned u = __builtin_bit_cast(unsigned, f);
  u += 0x7FFFu + ((u >> 16) & 1u);
  return (unsigned short)(u >> 16);
}
static __device__ __forceinline__ float bf2f(unsigned short h) {
  unsigned u = ((unsigned)h) << 16;
  return __builtin_bit_cast(float, u);
}

// --------- W1 -> transposed hi/lo bf16 tables [256][KP], zero-padded ---------
__global__ void w1t_kernel(const float* __restrict__ W1,
    unsigned short* __restrict__ hi, unsigned short* __restrict__ lo) {
  int idx = blockIdx.x * 256 + threadIdx.x;
  if (idx >= 256 * KP) return;
  int n = idx / KP, k = idx % KP;
  float v = (k < K1) ? W1[(long)k * 256 + n] : 0.f;
  unsigned short h = f2bf(v);
  hi[idx] = h;
  lo[idx] = f2bf(v - bf2f(h));
}

// --------- GEMM1 via split-bf16 MFMA: C[M,256] = A[M,K1] @ W1 ---------
// block: 512 thr = 8 waves (2x4). BM=64, BN=256, BK=32.
// LDS rows: 8 slots x 8 ushort (16B); slots 0-3 = hi(kb), 4-7 = lo(kb);
// slot swizzled s^(row&7).
__global__ __launch_bounds__(512) void gemm1_mfma_kernel(
    const float* __restrict__ A, const unsigned short* __restrict__ Bhi,
    const unsigned short* __restrict__ Blo, float* __restrict__ C, int M) {
  __shared__ unsigned short As[64 * 64];    // 8 KB
  __shared__ unsigned short Bs[256 * 64];   // 32 KB
  const int t = threadIdx.x;
  const int w = t >> 6, l = t & 63;
  const int wm = w >> 2, wn = w & 3;
  const int row0 = blockIdx.x * 64;

  f32x4 acc[2][4];
#pragma unroll
  for (int mi = 0; mi < 2; ++mi)
#pragma unroll
    for (int ni = 0; ni < 4; ++ni)
#pragma unroll
      for (int r = 0; r < 4; ++r) acc[mi][ni][r] = 0.f;

  const int am = t >> 3;          // A stage: row 0..63
  const int akq = (t & 7) * 4;    // k offset 0,4,...,28
  const int bn = t >> 1;          // B stage: row 0..255
  const int bhalf = t & 1;        // k half (0..15 / 16..31)
  const int lrow = l & 15, kb = l >> 4;
  const int swa = lrow & 7;

  for (int k0 = 0; k0 < KP; k0 += 32) {
    // ---- stage A (fp32 -> hi/lo bf16, swizzled)
    {
      int grow = row0 + am;
      float v[4];
#pragma unroll
      for (int i = 0; i < 4; ++i) {
        int gk = k0 + akq + i;
        v[i] = (grow < M && gk < K1) ? A[(long)grow * K1 + gk] : 0.f;
      }
      ushort4 h4, l4;
      unsigned short hh;
      hh = f2bf(v[0]); h4.x = hh; l4.x = f2bf(v[0] - bf2f(hh));
      hh = f2bf(v[1]); h4.y = hh; l4.y = f2bf(v[1] - bf2f(hh));
      hh = f2bf(v[2]); h4.z = hh; l4.z = f2bf(v[2] - bf2f(hh));
      hh = f2bf(v[3]); h4.w = hh; l4.w = f2bf(v[3] - bf2f(hh));
      int s = akq >> 3, o = akq & 7, sw = am & 7;
      *(ushort4*)&As[am * 64 + ((s ^ sw) * 8) + o] = h4;
      *(ushort4*)&As[am * 64 + (((s + 4) ^ sw) * 8) + o] = l4;
    }
    // ---- stage B (pre-converted bf16 hi/lo, swizzled)
    {
      const unsigned short* gh = Bhi + (long)bn * KP + k0 + bhalf * 16;
      const unsigned short* gl = Blo + (long)bn * KP + k0 + bhalf * 16;
      s16x8 h0 = *(const s16x8*)gh;
      s16x8 h1 = *(const s16x8*)(gh + 8);
      s16x8 l0 = *(const s16x8*)gl;
      s16x8 l1 = *(const s16x8*)(gl + 8);
      int s0 = bhalf * 2, sw = bn & 7;
      *(s16x8*)&Bs[bn * 64 + ((s0 ^ sw) * 8)] = h0;
      *(s16x8*)&Bs[bn * 64 + (((s0 + 1) ^ sw) * 8)] = h1;
      *(s16x8*)&Bs[bn * 64 + (((s0 + 4) ^ sw) * 8)] = l0;
      *(s16x8*)&Bs[bn * 64 + (((s0 + 5) ^ sw) * 8)] = l1;
    }
    __syncthreads();
    // ---- fragments + 24 MFMA
    {
      s16x8 ah[2], al[2], bh[4], bl[4];
#pragma unroll
      for (int mi = 0; mi < 2; ++mi) {
        int r = wm * 32 + mi * 16 + lrow;
        ah[mi] = *(const s16x8*)&As[r * 64 + ((kb ^ swa) * 8)];
        al[mi] = *(const s16x8*)&As[r * 64 + (((kb + 4) ^ swa) * 8)];
      }
#pragma unroll
      for (int ni = 0; ni < 4; ++ni) {
        int n = wn * 64 + ni * 16 + lrow;
        bh[ni] = *(const s16x8*)&Bs[n * 64 + ((kb ^ swa) * 8)];
        bl[ni] = *(const s16x8*)&Bs[n * 64 + (((kb + 4) ^ swa) * 8)];
      }
#pragma unroll
      for (int mi = 0; mi < 2; ++mi)
#pragma unroll
        for (int ni = 0; ni < 4; ++ni) {
          acc[mi][ni] = __builtin_amdgcn_mfma_f32_16x16x32_bf16(
              ah[mi], bh[ni], acc[mi][ni], 0, 0, 0);
          acc[mi][ni] = __builtin_amdgcn_mfma_f32_16x16x32_bf16(
              ah[mi], bl[ni], acc[mi][ni], 0, 0, 0);
          acc[mi][ni] = __builtin_amdgcn_mfma_f32_16x16x32_bf16(
              al[mi], bh[ni], acc[mi][ni], 0, 0, 0);
        }
    }
    __syncthreads();
  }
  // ---- epilogue: D lane layout col = l&15, row = (l>>4)*4 + r
  const int crow4 = (l >> 4) * 4;
  const int ccol = l & 15;
#pragma unroll
  for (int mi = 0; mi < 2; ++mi)
#pragma unroll
    for (int r = 0; r < 4; ++r) {
      int grow = row0 + wm * 32 + mi * 16 + crow4 + r;
      if (grow < M) {
#pragma unroll
        for (int ni = 0; ni < 4; ++ni)
          C[(long)grow * 256 + wn * 64 + ni * 16 + ccol] = acc[mi][ni][r];
      }
    }
}

// ---------------- per-node attention logits, layer 1 ----------------
__global__ void alpha1_kernel(const float* __restrict__ h1,
    const float* __restrict__ a_src, const float* __restrict__ a_dst,
    float* __restrict__ as_o, float* __restrict__ ad_o, int N) {
  int i = blockIdx.x * blockDim.x + threadIdx.x;  // i = n*8+h
  if (i >= N * 8) return;
  int h = i & 7;
  const float* hp = h1 + (long)(i >> 3) * 256 + h * 32;
  const float* sp = a_src + h * 32;
  const float* dp = a_dst + h * 32;
  float s1 = 0.f, s2 = 0.f;
#pragma unroll
  for (int c = 0; c < 32; c += 4) {
    float4 v = *(const float4*)(hp + c);
    float4 ws = *(const float4*)(sp + c);
    float4 wd = *(const float4*)(dp + c);
    s1 += v.x * ws.x + v.y * ws.y + v.z * ws.z + v.w * ws.w;
    s2 += v.x * wd.x + v.y * wd.y + v.z * wd.z + v.w * wd.w;
  }
  as_o[i] = s1;
  ad_o[i] = s2;
}

// ================= CSR construction =================
__global__ void hist_kernel(const int* __restrict__ dst, int* __restrict__ cnt,
                            int E, int N) {
  int e = blockIdx.x * blockDim.x + threadIdx.x;
  if (e >= E + N) return;
  int d = (e < E) ? dst[e] : (e - E);
  atomicAdd(&cnt[d], 1);
}

__global__ __launch_bounds__(1024) void scan_kernel(
    const int* __restrict__ cnt, int* __restrict__ rowptr,
    int* __restrict__ cursor, int N) {
  __shared__ int part[1024];
  const int tid = threadIdx.x;
  const int chunk = (N + 1023) / 1024;
  const int base = tid * chunk;
  const int lim = min(base + chunk, N);
  int sum = 0;
  for (int i = base; i < lim; ++i) sum += cnt[i];
  part[tid] = sum;
  __syncthreads();
  for (int off = 1; off < 1024; off <<= 1) {
    int v = (tid >= off) ? part[tid - off] : 0;
    __syncthreads();
    part[tid] += v;
    __syncthreads();
  }
  int run = (tid == 0) ? 0 : part[tid - 1];
  for (int i = base; i < lim; ++i) {
    rowptr[i] = run;
    cursor[i] = run;
    run += cnt[i];
  }
  if (tid == 1023) rowptr[N] = part[1023];
}

__global__ void scatter_kernel(const int* __restrict__ src,
    const int* __restrict__ dst, int* __restrict__ cursor,
    int* __restrict__ csr_src, int E, int N) {
  int e = blockIdx.x * blockDim.x + threadIdx.x;
  if (e >= E + N) return;
  int s, d;
  if (e < E) { s = src[e]; d = dst[e]; } else { s = e - E; d = s; }
  int pos = atomicAdd(&cursor[d], 1);
  csr_src[pos] = s;
}

// ======== layer-1 fused aggregation: wave per dst, no atomics ========
__global__ __launch_bounds__(256) void agg1_fused_kernel(
    const int* __restrict__ rowptr, const int* __restrict__ csr_src,
    const float* __restrict__ as_, const float* __restrict__ ad_,
    const float* __restrict__ h1, const float* __restrict__ bias,
    float* __restrict__ act, int N) {
  int d = blockIdx.x * 4 + (threadIdx.x >> 6);
  if (d >= N) return;
  int l = threadIdx.x & 63;
  int h = l >> 3;
  int rs = rowptr[d], re = rowptr[d + 1];
  float adv = ad_[d * 8 + h];
  float4 acc = make_float4(0.f, 0.f, 0.f, 0.f);
  float den = 0.f;
  for (int i = rs; i < re; ++i) {
    int s = csr_src[i];
    float a = __expf(leaky(as_[s * 8 + h] + adv));
    den += a;
    float4 v = *(const float4*)(h1 + (long)s * 256 + l * 4);
    acc.x += a * v.x; acc.y += a * v.y; acc.z += a * v.z; acc.w += a * v.w;
  }
  float inv = 1.f / den;
  float4 b = *(const float4*)(bias + l * 4);
  float4 o;
  o.x = acc.x * inv + b.x; o.y = acc.y * inv + b.y;
  o.z = acc.z * inv + b.z; o.w = acc.w * inv + b.w;
  o.x = o.x > 0.f ? o.x : expm1f(o.x);
  o.y = o.y > 0.f ? o.y : expm1f(o.y);
  o.z = o.z > 0.f ? o.z : expm1f(o.z);
  o.w = o.w > 0.f ? o.w : expm1f(o.w);
  *(float4*)(act + (long)d * 256 + l * 4) = o;
}

// ---------------- GEMM2 (K=256, N=56) + fused alpha2 ----------------
__global__ __launch_bounds__(256) void gemm2_kernel(const float* __restrict__ act,
    const float* __restrict__ W2, const float* __restrict__ a_src2,
    const float* __restrict__ a_dst2, float* __restrict__ h2,
    float* __restrict__ as_o, float* __restrict__ ad_o, int N) {
  __shared__ float Ws[256 * 56];
  for (int i = threadIdx.x; i < 256 * 56; i += 256) Ws[i] = W2[i];
  __syncthreads();
  int n = blockIdx.x * 32 + (threadIdx.x >> 3);
  int h = threadIdx.x & 7;
  if (n >= N) return;
  const float* ap = act + (long)n * 256;
  float acc[7] = {0.f, 0.f, 0.f, 0.f, 0.f, 0.f, 0.f};
  for (int k0 = 0; k0 < 256; k0 += 4) {
    float4 a = *(const float4*)(ap + k0);
    float av[4] = {a.x, a.y, a.z, a.w};
#pragma unroll
    for (int kk = 0; kk < 4; ++kk) {
      const float* wp = &Ws[(k0 + kk) * 56 + h * 7];
#pragma unroll
      for (int j = 0; j < 7; ++j) acc[j] += av[kk] * wp[j];
    }
  }
  float* hp = h2 + (long)n * 56 + h * 7;
  float s1 = 0.f, s2 = 0.f;
#pragma unroll
  for (int j = 0; j < 7; ++j) {
    hp[j] = acc[j];
    s1 += acc[j] * a_src2[h * 7 + j];
    s2 += acc[j] * a_dst2[h * 7 + j];
  }
  as_o[n * 8 + h] = s1;
  ad_o[n * 8 + h] = s2;
}

// ======== layer-2 fused aggregation: wave per dst ========
__global__ __launch_bounds__(256) void agg2_fused_kernel(
    const int* __restrict__ rowptr, const int* __restrict__ csr_src,
    const float* __restrict__ as_, const float* __restrict__ ad_,
    const float* __restrict__ h2, const float* __restrict__ bias,
    float* __restrict__ out, int N) {
  int d = blockIdx.x * 4 + (threadIdx.x >> 6);
  if (d >= N) return;
  int l = threadIdx.x & 63;
  int h = l >> 3, j = l & 7;
  int rs = rowptr[d], re = rowptr[d + 1];
  float adv = ad_[d * 8 + h];
  float acc = 0.f, den = 0.f;
  for (int i = rs; i < re; ++i) {
    int s = csr_src[i];
    float a = __expf(leaky(as_[s * 8 + h] + adv));
    den += a;
    if (j < 7) acc += a * h2[(long)s * 56 + h * 7 + j];
  }
  if (j < 7) out[(long)d * 56 + h * 7 + j] = acc / den + bias[h * 7 + j];
}

extern "C" void kernel_launch(void* const* d_in, const int* in_sizes, int n_in,
                              void* d_out, int out_size, void* d_ws, size_t ws_size,
                              hipStream_t stream) {
  const float* x    = (const float*)d_in[0];
  const int*   ei   = (const int*)d_in[1];
  const float* W1   = (const float*)d_in[2];
  const float* asr1 = (const float*)d_in[3];
  const float* adt1 = (const float*)d_in[4];
  const float* b1   = (const float*)d_in[5];
  const float* W2   = (const float*)d_in[6];
  const float* asr2 = (const float*)d_in[7];
  const float* adt2 = (const float*)d_in[8];
  const float* b2   = (const float*)d_in[9];
  float* out = (float*)d_out;

  const int N = in_sizes[0] / K1;
  const int E = in_sizes[1] / 2;
  const int* src = ei;
  const int* dst = ei + E;

  float* ws = (float*)d_ws;
  float* h1  = ws; ws += (long)N * 256;
  float* act = ws; ws += (long)N * 256;
  float* h2  = ws; ws += (long)N * 56;
  float* as1 = ws; ws += N * 8;
  float* ad1 = ws; ws += N * 8;
  float* as2 = ws; ws += N * 8;
  float* ad2 = ws; ws += N * 8;
  unsigned short* w1hi = (unsigned short*)ws; ws += 256 * KP / 2;
  unsigned short* w1lo = (unsigned short*)ws; ws += 256 * KP / 2;
  int* cnt     = (int*)ws; ws += N;
  int* rowptr  = (int*)ws; ws += N + 1;
  int* cursor  = (int*)ws; ws += N;
  int* csr_src = (int*)ws; ws += E + N;

  hipMemsetAsync(cnt, 0, (size_t)N * sizeof(int), stream);

  dim3 blk(256);

  // CSR build + weight conversion (cheap)
  hist_kernel<<<dim3((E + N + 255) / 256), blk, 0, stream>>>(dst, cnt, E, N);
  scan_kernel<<<dim3(1), dim3(1024), 0, stream>>>(cnt, rowptr, cursor, N);
  scatter_kernel<<<dim3((E + N + 255) / 256), blk, 0, stream>>>(
      src, dst, cursor, csr_src, E, N);
  w1t_kernel<<<dim3((256 * KP + 255) / 256), blk, 0, stream>>>(W1, w1hi, w1lo);

  gemm1_mfma_kernel<<<dim3((N + 63) / 64), dim3(512), 0, stream>>>(
      x, w1hi, w1lo, h1, N);
  alpha1_kernel<<<dim3((N * 8 + 255) / 256), blk, 0, stream>>>(h1, asr1, adt1, as1, ad1, N);
  agg1_fused_kernel<<<dim3((N + 3) / 4), blk, 0, stream>>>(
      rowptr, csr_src, as1, ad1, h1, b1, act, N);
  gemm2_kernel<<<dim3((N + 31) / 32), blk, 0, stream>>>(act, W2, asr2, adt2, h2, as2, ad2, N);
  agg2_fused_kernel<<<dim3((N + 3) / 4), blk, 0, stream>>>(
      rowptr, csr_src, as2, ad2, h2, b2, out, N);
}